// Round 2
// baseline (782.802 us; speedup 1.0000x reference)
//
#include <hip/hip_runtime.h>
#include <stdint.h>

typedef short v8s __attribute__((ext_vector_type(8)));
typedef short v4s __attribute__((ext_vector_type(4)));
typedef float v4f __attribute__((ext_vector_type(4)));

#define NTOK 8192
#define HIDD 2048
#define NH 16
#define HD 128
#define CHUNK 256
#define NCH 32
#define NQKV 6144

__device__ __forceinline__ float bf2f(short s){
  return __uint_as_float(((unsigned)(unsigned short)s) << 16);
}
__device__ __forceinline__ short f2bf(float f){
  unsigned u = __float_as_uint(f);
  unsigned r = (u + 0x7fffu + ((u >> 16) & 1u)) >> 16;
  return (short)r;
}
__device__ __forceinline__ float slope_of(int h){
  // start = 2^-0.5 ; s_h = start^(h+1) * (1 + 1e-5)
  return exp2f(-0.5f * (float)(h + 1)) * 1.00001f;
}

// proper addrspacecast (CK pattern): generic->AS1 for global, generic->AS3 for LDS
__device__ __forceinline__ void gload_lds16(const void* g, void* l){
  __builtin_amdgcn_global_load_lds(
      (__attribute__((address_space(1))) void*)(g),
      (__attribute__((address_space(3))) void*)(l),
      16, 0, 0);
}

// ---------------- rope cos/sin table: tab[n][0..63]=cos, [64..127]=sin ----
__global__ void rope_table_k(const int* __restrict__ pos, float* __restrict__ tab){
  int n = blockIdx.x;
  int i = threadIdx.x; // 64 threads
  float p = (float)pos[n];
  float ex = (float)i * (1.0f / 64.0f);
  float invf = expf(-ex * logf(600000.0f));
  float fr = p * invf;
  tab[n * 128 + i] = cosf(fr);
  tab[n * 128 + 64 + i] = sinf(fr);
}

// ---------------- f32 -> bf16 convert (vectorized) ------------------------
__global__ void cvt_k(const float* __restrict__ in, short* __restrict__ outp, int n4){
  int i = blockIdx.x * 256 + threadIdx.x;
  if(i >= n4) return;
  v4f x = *(const v4f*)(in + (long)i * 4);
  v4s y;
#pragma unroll
  for(int j = 0; j < 4; j++) y[j] = f2bf(x[j]);
  *(v4s*)(outp + (long)i * 4) = y;
}

// ---------------- transpose + convert: in (R,C) f32 -> out (C,R) bf16 -----
__global__ void tconv_k(const float* __restrict__ in, short* __restrict__ outp, int R, int C){
  __shared__ float tl[32][33];
  int c0 = blockIdx.x * 32, r0 = blockIdx.y * 32;
  int tx = threadIdx.x & 31, ty = threadIdx.x >> 5;
#pragma unroll
  for(int ii = 0; ii < 4; ii++){
    int r = ty + ii * 8;
    tl[r][tx] = in[(long)(r0 + r) * C + c0 + tx];
  }
  __syncthreads();
#pragma unroll
  for(int ii = 0; ii < 4; ii++){
    int r = ty + ii * 8;
    outp[(long)(c0 + r) * R + r0 + tx] = f2bf(tl[tx][r]);
  }
}

// ---------------- GEMM: C(M,Nn) = A(M,K) @ Bt(Nn,K)^T, bf16 in, f32 acc ---
// EPI 0: plain f32 out. EPI 1: bf16 scatter to (role,h,n,d). EPI 2: bf16 sigmoid.
template<int EPI>
__global__ __launch_bounds__(256)
void gemm_bt_k(const short* __restrict__ A, const short* __restrict__ Bt,
               float* __restrict__ FO, short* __restrict__ SO,
               int M, int Nn, int K)
{
  __shared__ __align__(16) short sA[2][128 * 32];
  __shared__ __align__(16) short sB[2][128 * 32];
  const int t = threadIdx.x;
  const int lane = t & 63;
  const int w = t >> 6;
  const int wm = w >> 1, wn = w & 1;
  const int m0 = blockIdx.y * 128, n0 = blockIdx.x * 128;

  auto stage = [&](int buf, int k0){
#pragma unroll
    for(int j = 0; j < 2; j++){
      int L = j * 256 + t;
      int row = L >> 2;
      int co = (L & 3) << 3;
      short* lb_a = &sA[buf][(j * 256 + w * 64) * 8];
      short* lb_b = &sB[buf][(j * 256 + w * 64) * 8];
      gload_lds16(A + (long)(m0 + row) * K + k0 + co, lb_a);
      gload_lds16(Bt + (long)(n0 + row) * K + k0 + co, lb_b);
    }
  };

  v4f acc[4][4];
#pragma unroll
  for(int i = 0; i < 4; i++)
#pragma unroll
    for(int j = 0; j < 4; j++) acc[i][j] = (v4f){0.f, 0.f, 0.f, 0.f};

  const int nk = K >> 5;
  stage(0, 0);
  for(int kt = 0; kt < nk; ++kt){
    __syncthreads();
    const int cur = kt & 1;
    if(kt + 1 < nk) stage(cur ^ 1, (kt + 1) << 5);
    const int lrow = lane & 15;
    const int kofs = (lane >> 4) << 3;
    v8s af[4], bfr[4];
#pragma unroll
    for(int mi = 0; mi < 4; mi++) af[mi] = *(const v8s*)&sA[cur][(wm * 64 + mi * 16 + lrow) * 32 + kofs];
#pragma unroll
    for(int ni = 0; ni < 4; ni++) bfr[ni] = *(const v8s*)&sB[cur][(wn * 64 + ni * 16 + lrow) * 32 + kofs];
#pragma unroll
    for(int mi = 0; mi < 4; mi++)
#pragma unroll
      for(int ni = 0; ni < 4; ni++)
        acc[mi][ni] = __builtin_amdgcn_mfma_f32_16x16x32_bf16(af[mi], bfr[ni], acc[mi][ni], 0, 0, 0);
  }

  const int crow = (lane >> 4) << 2;
  const int ccol = lane & 15;
#pragma unroll
  for(int mi = 0; mi < 4; mi++){
#pragma unroll
    for(int ni = 0; ni < 4; ni++){
#pragma unroll
      for(int r = 0; r < 4; r++){
        int gr = m0 + wm * 64 + mi * 16 + crow + r;
        int gc = n0 + wn * 64 + ni * 16 + ccol;
        float vv = acc[mi][ni][r];
        if(EPI == 0){
          FO[(long)gr * Nn + gc] = vv;
        } else if(EPI == 1){
          int role = gc >> 11, hh = (gc >> 7) & 15, dd = gc & 127;
          SO[(((long)role * NH + hh) * NTOK + gr) * HD + dd] = f2bf(vv);
        } else {
          SO[(long)gr * Nn + gc] = f2bf(1.0f / (1.0f + expf(-vv)));
        }
      }
    }
  }
}

// ---------------- rope in place on q (role 0, + scale) and k (role 1) -----
__global__ void rope_k(short* __restrict__ qkv, const float* __restrict__ tab){
  long idx = (long)blockIdx.x * 256 + threadIdx.x; // 2*16*8192*8 threads
  int i8 = (int)(idx & 7);
  long rest = idx >> 3;
  int n = (int)(rest & 8191); rest >>= 13;
  int h = (int)(rest & 15);
  int role = (int)(rest >> 4);
  int i0 = i8 * 8;
  long base = (((long)role * NH + h) * NTOK + n) * HD;
  v8s x1 = *(const v8s*)(qkv + base + i0);
  v8s x2 = *(const v8s*)(qkv + base + 64 + i0);
  v4f c0 = *(const v4f*)(tab + n * 128 + i0);
  v4f c1 = *(const v4f*)(tab + n * 128 + i0 + 4);
  v4f s0 = *(const v4f*)(tab + n * 128 + 64 + i0);
  v4f s1 = *(const v4f*)(tab + n * 128 + 64 + i0 + 4);
  float sc = (role == 0) ? 0.08838834764831845f : 1.0f; // D^-0.5 on q
  v8s o1, o2;
#pragma unroll
  for(int j = 0; j < 4; j++){
    float a = bf2f(x1[j]), b = bf2f(x2[j]);
    o1[j] = f2bf((a * c0[j] - b * s0[j]) * sc);
    o2[j] = f2bf((b * c0[j] + a * s0[j]) * sc);
  }
#pragma unroll
  for(int j = 0; j < 4; j++){
    float a = bf2f(x1[4 + j]), b = bf2f(x2[4 + j]);
    o1[4 + j] = f2bf((a * c1[j] - b * s1[j]) * sc);
    o2[4 + j] = f2bf((b * c1[j] + a * s1[j]) * sc);
  }
  *(v8s*)(qkv + base + i0) = o1;
  *(v8s*)(qkv + base + 64 + i0) = o2;
}

// ---------------- per (h,c): S^T[e][d] = sum_n v[n][e] * k[n][d] * kdec[n]
__global__ __launch_bounds__(256)
void skernel(const short* __restrict__ qkv, float* __restrict__ Sb){
  int c = blockIdx.x, h = blockIdx.y;
  float s = slope_of(h);
  __shared__ __align__(16) short kT[128][40]; // stride 40 shorts = 80 B
  __shared__ __align__(16) short vT[128][40];
  const int t = threadIdx.x, lane = t & 63, w = t >> 6;
  const int wm = w >> 1, wn = w & 1;
  const short* kb = qkv + (((long)NH + h) * NTOK + c * CHUNK) * HD;
  const short* vb = qkv + (((long)2 * NH + h) * NTOK + c * CHUNK) * HD;
  v4f acc[4][4];
#pragma unroll
  for(int i = 0; i < 4; i++)
#pragma unroll
    for(int j = 0; j < 4; j++) acc[i][j] = (v4f){0.f, 0.f, 0.f, 0.f};

  for(int n0 = 0; n0 < CHUNK; n0 += 32){
    __syncthreads();
#pragma unroll
    for(int rep = 0; rep < 2; rep++){
      int L = rep * 256 + t;
      int nn = L >> 4, d0 = (L & 15) << 3;
      v8s kx = *(const v8s*)(kb + (long)(n0 + nn) * HD + d0);
      v8s vx = *(const v8s*)(vb + (long)(n0 + nn) * HD + d0);
      float kd = expf(-s * (float)(255 - (n0 + nn)));
#pragma unroll
      for(int j = 0; j < 8; j++){
        kT[d0 + j][nn] = f2bf(bf2f(kx[j]) * kd);
        vT[d0 + j][nn] = vx[j];
      }
    }
    __syncthreads();
    const int lrow = lane & 15, kofs = (lane >> 4) << 3;
    v8s af[4], bfr[4];
#pragma unroll
    for(int ei = 0; ei < 4; ei++) af[ei] = *(const v8s*)&vT[wm * 64 + ei * 16 + lrow][kofs];
#pragma unroll
    for(int di = 0; di < 4; di++) bfr[di] = *(const v8s*)&kT[wn * 64 + di * 16 + lrow][kofs];
#pragma unroll
    for(int ei = 0; ei < 4; ei++)
#pragma unroll
      for(int di = 0; di < 4; di++)
        acc[ei][di] = __builtin_amdgcn_mfma_f32_16x16x32_bf16(af[ei], bfr[di], acc[ei][di], 0, 0, 0);
  }
  float* ob = Sb + ((long)h * NCH + c) * (HD * HD);
  const int crow = (lane >> 4) << 2, ccol = lane & 15;
#pragma unroll
  for(int ei = 0; ei < 4; ei++)
#pragma unroll
    for(int di = 0; di < 4; di++)
#pragma unroll
      for(int r = 0; r < 4; r++)
        ob[(long)(wm * 64 + ei * 16 + crow + r) * HD + wn * 64 + di * 16 + ccol] = acc[ei][di][r];
}

// ---------------- decay-scan over chunks: kvT state BEFORE chunk c --------
__global__ void scan_k(const float* __restrict__ Sb, short* __restrict__ kvb){
  int idx = blockIdx.x * 256 + threadIdx.x; // 16 * 16384
  int h = idx >> 14, ed = idx & 16383;
  float bd = expf(-slope_of(h) * 256.0f);
  float a = 0.f;
  for(int c = 0; c < NCH; c++){
    long o = ((long)h * NCH + c) * 16384 + ed;
    kvb[o] = f2bf(a);
    a = bd * a + Sb[o];
  }
}

// ---------------- attention output: o_inter + o_intra -> bf16 attnb ------
__global__ __launch_bounds__(256)
void attn_k(const short* __restrict__ qkv, const short* __restrict__ kvb,
            short* __restrict__ attnb){
  const int c = blockIdx.x, mt = blockIdx.y, h = blockIdx.z;
  const int t = threadIdx.x, lane = t & 63, w = t >> 6;
  const float s = slope_of(h);
  __shared__ __align__(16) short Kl[64 * 128];   // XOR-swizzled
  __shared__ __align__(16) short VT[128][72];    // transposed V chunk
  const int lrow = lane & 15, kg = lane >> 4;
  const int mbase = mt * 64 + w * 16;

  const short* qb = qkv + (((long)h) * NTOK + c * CHUNK + mbase) * HD;
  v8s qf[4];
#pragma unroll
  for(int kc = 0; kc < 4; kc++)
    qf[kc] = *(const v8s*)(qb + (long)lrow * HD + kc * 32 + kg * 8);

  v4f acc[8];
#pragma unroll
  for(int ei = 0; ei < 8; ei++) acc[ei] = (v4f){0.f, 0.f, 0.f, 0.f};

  // phase 1: o_inter = (q @ kvT^T), then row-scale by q_decay
  const short* kvt = kvb + ((long)h * NCH + c) * 16384;
#pragma unroll
  for(int ei = 0; ei < 8; ei++)
#pragma unroll
    for(int kc = 0; kc < 4; kc++){
      v8s bfr = *(const v8s*)(kvt + (long)(ei * 16 + lrow) * HD + kc * 32 + kg * 8);
      acc[ei] = __builtin_amdgcn_mfma_f32_16x16x32_bf16(qf[kc], bfr, acc[ei], 0, 0, 0);
    }
  float qd[4];
#pragma unroll
  for(int r = 0; r < 4; r++) qd[r] = expf(-s * (float)(mbase + kg * 4 + r + 1));
#pragma unroll
  for(int ei = 0; ei < 8; ei++)
#pragma unroll
    for(int r = 0; r < 4; r++) acc[ei][r] *= qd[r];

  // phase 2: o_intra, n-chunks of 64 up to and including mt
  const short* kbase = qkv + (((long)NH + h) * NTOK + c * CHUNK) * HD;
  const short* vbase = qkv + (((long)2 * NH + h) * NTOK + c * CHUNK) * HD;
  for(int nc = 0; nc <= mt; nc++){
    __syncthreads();
#pragma unroll
    for(int rep = 0; rep < 4; rep++){
      int L = rep * 256 + t;
      int nn = L >> 4, d0 = (L & 15) << 3;
      v8s kx = *(const v8s*)(kbase + ((long)nc * 64 + nn) * HD + d0);
      int ba = (nn << 8) + (d0 << 1); ba ^= (nn & 7) << 4;
      *(v8s*)((char*)Kl + ba) = kx;
      v8s vx = *(const v8s*)(vbase + ((long)nc * 64 + nn) * HD + d0);
#pragma unroll
      for(int j = 0; j < 8; j++) VT[d0 + j][nn] = vx[j];
    }
    __syncthreads();
    const int m_gl = mbase + lrow;
#pragma unroll
    for(int nf = 0; nf < 4; nf++){
      v4f pT = (v4f){0.f, 0.f, 0.f, 0.f};
#pragma unroll
      for(int kc = 0; kc < 4; kc++){
        int rr = nf * 16 + lrow;
        int ba = (rr << 8) + ((kc * 32 + kg * 8) << 1); ba ^= (rr & 7) << 4;
        v8s kf = *(const v8s*)((char*)Kl + ba);
        pT = __builtin_amdgcn_mfma_f32_16x16x32_bf16(kf, qf[kc], pT, 0, 0, 0); // P^T = K @ Q^T
      }
      v4s pb;
#pragma unroll
      for(int r = 0; r < 4; r++){
        int n_gl = nc * 64 + nf * 16 + kg * 4 + r;
        float f = (n_gl <= m_gl) ? expf(-s * (float)(m_gl - n_gl)) : 0.f;
        pb[r] = f2bf(pT[r] * f);
      }
#pragma unroll
      for(int ei = 0; ei < 8; ei++){
        v4s vf = *(const v4s*)&VT[ei * 16 + lrow][nf * 16 + kg * 4];
        acc[ei] = __builtin_amdgcn_mfma_f32_16x16x16bf16_1k(pb, vf, acc[ei], 0, 0, 0);
      }
    }
  }

  short* ob = attnb + (long)(c * CHUNK + mbase) * HIDD + h * HD;
#pragma unroll
  for(int ei = 0; ei < 8; ei++)
#pragma unroll
    for(int r = 0; r < 4; r++)
      ob[(long)(kg * 4 + r) * HIDD + ei * 16 + lrow] = f2bf(acc[ei][r]);
}

// ---------------- RMS norm * g_norm_weight * sigmoid(gate) -> bf16 y ------
__global__ __launch_bounds__(256)
void rmsgate_k(const short* __restrict__ attnb, const short* __restrict__ gsig,
               const float* __restrict__ gnw, short* __restrict__ yb){
  int n = blockIdx.x, t = threadIdx.x;
  v8s x = *(const v8s*)(attnb + (long)n * HIDD + t * 8);
  float xf[8]; float ssq = 0.f;
#pragma unroll
  for(int j = 0; j < 8; j++){ xf[j] = bf2f(x[j]); ssq += xf[j] * xf[j]; }
  for(int o = 32; o > 0; o >>= 1) ssq += __shfl_down(ssq, o, 64);
  __shared__ float rl[4];
  int lane = t & 63, w = t >> 6;
  if(lane == 0) rl[w] = ssq;
  __syncthreads();
  float tot = rl[0] + rl[1] + rl[2] + rl[3];
  float rms = rsqrtf(tot * (1.0f / 2048.0f) + 1e-5f);
  v8s g = *(const v8s*)(gsig + (long)n * HIDD + t * 8);
  v4f w0 = *(const v4f*)(gnw + t * 8);
  v4f w1 = *(const v4f*)(gnw + t * 8 + 4);
  v8s y;
#pragma unroll
  for(int j = 0; j < 4; j++) y[j] = f2bf(xf[j] * rms * w0[j] * bf2f(g[j]));
#pragma unroll
  for(int j = 0; j < 4; j++) y[4 + j] = f2bf(xf[4 + j] * rms * w1[j] * bf2f(g[4 + j]));
  *(v8s*)(yb + (long)n * HIDD + t * 8) = y;
}

extern "C" void kernel_launch(void* const* d_in, const int* in_sizes, int n_in,
                              void* d_out, int out_size, void* d_ws, size_t ws_size,
                              hipStream_t stream)
{
  (void)in_sizes; (void)n_in; (void)out_size; (void)ws_size;
  const float* hidden = (const float*)d_in[0];
  const int* positions = (const int*)d_in[1];
  const float* Wqkv = (const float*)d_in[2];
  const float* Wg = (const float*)d_in[3];
  const float* Wd = (const float*)d_in[4];
  const float* gnw = (const float*)d_in[5];
  float* out = (float*)d_out;

  // ---- workspace plan (peak 152 MiB) with lifetime overlays ----
  // ws:   [hbf 33.5MB | wtr 25.2MB | qkvbf 100.7MB]
  //   hbf: hidden bf16 (cvt -> gate gemm), then reused as yb
  //   wtr: WqkvT (->gemm1); then kvb@+0, tab@+16.78M, WgT@+16.78M; WdT@+0
  // d_out (67.1MB): Sb f32 @0 (skernel->scan); attnb bf16 @0 (attn->rmsgate);
  //                 gsig bf16 @33.55M (gate gemm->rmsgate); final gemm overwrites.
  char* ws = (char*)d_ws;
  const size_t HBF_B = (size_t)NTOK * HIDD * 2;          // 33,554,432
  const size_t WTR_B = (size_t)NQKV * HIDD * 2;          // 25,165,824
  const size_t KVB_B = (size_t)NH * NCH * HD * HD * 2;   // 16,777,216
  short* hbf   = (short*)(ws);
  short* yb    = hbf;                                    // reuse after gate gemm
  char*  wtr   = ws + HBF_B;
  short* wqkvT = (short*)(wtr);
  short* kvb   = (short*)(wtr);
  float* tab   = (float*)(wtr + KVB_B);
  short* wgT   = (short*)(wtr + KVB_B);
  short* wdT   = (short*)(wtr);
  short* qkvbf = (short*)(ws + HBF_B + WTR_B);
  float* Sb    = (float*)(d_out);
  short* attnb = (short*)(d_out);
  short* gsig  = (short*)((char*)d_out + (size_t)NTOK * HIDD * 2);

  // 1-3: hidden->bf16, WqkvT, qkv gemm (scatter to (role,h,n,d) bf16)
  cvt_k<<<(NTOK * HIDD / 4) / 256, 256, 0, stream>>>(hidden, hbf, NTOK * HIDD / 4);
  tconv_k<<<dim3(NQKV / 32, HIDD / 32), 256, 0, stream>>>(Wqkv, wqkvT, HIDD, NQKV);
  gemm_bt_k<1><<<dim3(NQKV / 128, NTOK / 128), 256, 0, stream>>>(hbf, wqkvT, nullptr, qkvbf, NTOK, NQKV, HIDD);

  // 4-5: rope (table after gemm1 -- tab overlays dead WqkvT region)
  rope_table_k<<<NTOK, 64, 0, stream>>>(positions, tab);
  rope_k<<<(2 * NH * NTOK * 8) / 256, 256, 0, stream>>>(qkvbf, tab);

  // 6-8: lightning attention
  skernel<<<dim3(NCH, NH), 256, 0, stream>>>(qkvbf, Sb);
  scan_k<<<(NH * HD * HD) / 256, 256, 0, stream>>>(Sb, kvb);
  attn_k<<<dim3(NCH, 4, NH), 256, 0, stream>>>(qkvbf, kvb, attnb);

  // 9-10: gate gemm (sigmoid, bf16) -- after attention so gsig fits in d_out
  tconv_k<<<dim3(HIDD / 32, HIDD / 32), 256, 0, stream>>>(Wg, wgT, HIDD, HIDD);
  gemm_bt_k<2><<<dim3(HIDD / 128, NTOK / 128), 256, 0, stream>>>(hbf, wgT, nullptr, gsig, NTOK, HIDD, HIDD);

  // 11: rms-norm * weight * sigmoid(gate) -> yb (reuses hbf)
  rmsgate_k<<<NTOK, 256, 0, stream>>>(attnb, gsig, gnw, yb);

  // 12-13: output gemm
  tconv_k<<<dim3(HIDD / 32, HIDD / 32), 256, 0, stream>>>(Wd, wdT, HIDD, HIDD);
  gemm_bt_k<0><<<dim3(HIDD / 128, NTOK / 128), 256, 0, stream>>>(yb, wdT, out, nullptr, NTOK, HIDD, HIDD);
}

// Round 5
// 696.102 us; speedup vs baseline: 1.1246x; 1.1246x over previous
//
#include <hip/hip_runtime.h>
#include <stdint.h>

typedef short v8s __attribute__((ext_vector_type(8)));
typedef short v4s __attribute__((ext_vector_type(4)));
typedef float v4f __attribute__((ext_vector_type(4)));

#define NTOK 8192
#define HIDD 2048
#define NH 16
#define HD 128
#define CHUNK 256
#define NCH 32
#define NQKV 6144
#define KD 2048   // K of all three GEMMs

#define VMCNT(n) asm volatile("s_waitcnt vmcnt(" #n ")" ::: "memory")
#define BARRIER() asm volatile("s_barrier" ::: "memory")

__device__ __forceinline__ float bf2f(short s){
  return __uint_as_float(((unsigned)(unsigned short)s) << 16);
}
__device__ __forceinline__ short f2bf(float f){
  unsigned u = __float_as_uint(f);
  unsigned r = (u + 0x7fffu + ((u >> 16) & 1u)) >> 16;
  return (short)r;
}
__device__ __forceinline__ float slope_of(int h){
  return exp2f(-0.5f * (float)(h + 1)) * 1.00001f;
}

// proper addrspacecast (CK pattern)
__device__ __forceinline__ void gload_lds16(const void* g, void* l){
  __builtin_amdgcn_global_load_lds(
      (__attribute__((address_space(1))) void*)(g),
      (__attribute__((address_space(3))) void*)(l),
      16, 0, 0);
}

// ---------------- rope cos/sin table ----------------
__global__ void rope_table_k(const int* __restrict__ pos, float* __restrict__ tab){
  int n = blockIdx.x;
  int i = threadIdx.x; // 64 threads
  float p = (float)pos[n];
  float ex = (float)i * (1.0f / 64.0f);
  float invf = expf(-ex * logf(600000.0f));
  float fr = p * invf;
  tab[n * 128 + i] = cosf(fr);
  tab[n * 128 + 64 + i] = sinf(fr);
}

// ---------------- f32 -> bf16 convert ----------------
__global__ void cvt_k(const float* __restrict__ in, short* __restrict__ outp, int n4){
  int i = blockIdx.x * 256 + threadIdx.x;
  if(i >= n4) return;
  v4f x = *(const v4f*)(in + (long)i * 4);
  v4s y;
#pragma unroll
  for(int j = 0; j < 4; j++) y[j] = f2bf(x[j]);
  *(v4s*)(outp + (long)i * 4) = y;
}

// ---------------- transpose + convert ----------------
__global__ void tconv_k(const float* __restrict__ in, short* __restrict__ outp, int R, int C){
  __shared__ float tl[32][33];
  int c0 = blockIdx.x * 32, r0 = blockIdx.y * 32;
  int tx = threadIdx.x & 31, ty = threadIdx.x >> 5;
#pragma unroll
  for(int ii = 0; ii < 4; ii++){
    int r = ty + ii * 8;
    tl[r][tx] = in[(long)(r0 + r) * C + c0 + tx];
  }
  __syncthreads();
#pragma unroll
  for(int ii = 0; ii < 4; ii++){
    int r = ty + ii * 8;
    outp[(long)(c0 + r) * R + r0 + tx] = f2bf(tl[tx][r]);
  }
}

// ======== 256x256 8-phase GEMM: C(M,Nn) = A(M,K) @ Bt(Nn,K)^T =========
// LDS map (shorts): A: buf*16384 + ks*8192 + row*32 + slot*8   (rows 0..255)
//                   B: 32768 + same.  swizzle: slot ^= (row>>1)&3 (both sides)
// phases per K-tile (mq=p&1, ks=p>>1); B-frags held in regs per ks.
// stages: p0 -> {Aks1,Bks1}(kt+1) into other buf; p2 -> Bks0(kt+2),
// p3 -> Aks0(kt+2) into cur buf (regions fully read & barrier-retired).
// counted waits: end-p1 vmcnt(8|0); end-p3 vmcnt(8|4|0). Never drain mid-loop.
template<int EPI>
__global__ __launch_bounds__(512, 2)
void gemm256_k(const short* __restrict__ A, const short* __restrict__ Bt,
               float* __restrict__ FO, short* __restrict__ SO, int Nn)
{
  __shared__ __align__(16) short lds[65536]; // 128 KiB
  const int t = threadIdx.x;
  const int lane = t & 63;
  const int w = t >> 6;
  const int wm = w >> 2, wn = w & 3;
  const int lrow = lane & 15, kg = lane >> 4;
  const int bm = blockIdx.y * 256, bn = blockIdx.x * 256;
  const short* Arows = A + (long)bm * KD;
  const short* Brows = Bt + (long)bn * KD;
  const int r0 = t >> 2;
  const int sc0 = ((t & 3) ^ ((r0 >> 1) & 3)) << 3; // pre-swizzled source col (bf16)

  auto stage = [&](const short* rows, int mat, int buf, int ks, int kt2){
    short* dst = &lds[mat * 32768 + buf * 16384 + ks * 8192];
    long koff = (long)kt2 * 64 + ks * 32 + sc0;
    gload_lds16(rows + (long)r0 * KD + koff, dst + t * 8);
    gload_lds16(rows + (long)(r0 + 128) * KD + koff, dst + (512 + t) * 8);
  };
  auto loadA = [&](v8s* aA, int buf, int mq, int ks){
#pragma unroll
    for(int m = 0; m < 4; m++){
      int row = wm * 128 + mq * 64 + m * 16 + lrow;
      int slot = kg ^ ((row >> 1) & 3);
      aA[m] = *(const v8s*)&lds[buf * 16384 + ks * 8192 + row * 32 + slot * 8];
    }
  };
  auto loadB = [&](v8s* bb, int buf, int ks){
#pragma unroll
    for(int n = 0; n < 4; n++){
      int row = wn * 64 + n * 16 + lrow;
      int slot = kg ^ ((row >> 1) & 3);
      bb[n] = *(const v8s*)&lds[32768 + buf * 16384 + ks * 8192 + row * 32 + slot * 8];
    }
  };

  v4f acc[8][4];
#pragma unroll
  for(int i = 0; i < 8; i++)
#pragma unroll
    for(int j = 0; j < 4; j++) acc[i][j] = (v4f){0.f, 0.f, 0.f, 0.f};

  auto mmac = [&](v8s* aA, v8s* bb, int mq){
    __builtin_amdgcn_s_setprio(1);
#pragma unroll
    for(int m = 0; m < 4; m++)
#pragma unroll
      for(int n = 0; n < 4; n++)
        acc[mq * 4 + m][n] = __builtin_amdgcn_mfma_f32_16x16x32_bf16(aA[m], bb[n], acc[mq * 4 + m][n], 0, 0, 0);
    __builtin_amdgcn_s_setprio(0);
  };

  const int nk = KD / 64; // 32
  // prologue: ks0(0), ks1(0), ks0(1)  [12 loads/thread]
  stage(Brows, 1, 0, 0, 0);
  stage(Arows, 0, 0, 0, 0);
  stage(Arows, 0, 0, 1, 0);
  stage(Brows, 1, 0, 1, 0);
  stage(Brows, 1, 1, 0, 1);
  stage(Arows, 0, 1, 0, 1);
  VMCNT(8);
  BARRIER();

  for(int kt = 0; kt < nk; ++kt){
    const int cur = kt & 1, nxt = cur ^ 1;
    v8s aA[4], bb[4];
    // ---- p0: mq0 ks0 ----
    loadB(bb, cur, 0);
    loadA(aA, cur, 0, 0);
    if(kt + 1 < nk){ stage(Arows, 0, nxt, 1, kt + 1); stage(Brows, 1, nxt, 1, kt + 1); }
    BARRIER();
    mmac(aA, bb, 0);
    BARRIER();
    // ---- p1: mq1 ks0 ----
    loadA(aA, cur, 1, 0);
    BARRIER();
    mmac(aA, bb, 1);
    if(kt + 1 < nk){ VMCNT(8); } else { VMCNT(0); }
    BARRIER();
    // ---- p2: mq0 ks1 ----
    loadB(bb, cur, 1);
    loadA(aA, cur, 0, 1);
    if(kt + 2 < nk) stage(Brows, 1, cur, 0, kt + 2);
    BARRIER();
    mmac(aA, bb, 0);
    BARRIER();
    // ---- p3: mq1 ks1 ----
    loadA(aA, cur, 1, 1);
    if(kt + 2 < nk) stage(Arows, 0, cur, 0, kt + 2);
    BARRIER();
    mmac(aA, bb, 1);
    if(kt + 2 < nk){ VMCNT(8); } else if(kt + 1 < nk){ VMCNT(4); } else { VMCNT(0); }
    BARRIER();
  }

  const int crow = kg << 2;  // (lane>>4)*4
  const int ccol = lane & 15;
#pragma unroll
  for(int m = 0; m < 8; m++){
#pragma unroll
    for(int n = 0; n < 4; n++){
#pragma unroll
      for(int r = 0; r < 4; r++){
        int gr = bm + wm * 128 + m * 16 + crow + r;
        int gc = bn + wn * 64 + n * 16 + ccol;
        float vv = acc[m][n][r];
        if(EPI == 0){
          FO[(long)gr * Nn + gc] = vv;
        } else if(EPI == 1){
          int role = gc >> 11, hh = (gc >> 7) & 15, dd = gc & 127;
          SO[(((long)role * NH + hh) * NTOK + gr) * HD + dd] = f2bf(vv);
        } else {
          SO[(long)gr * Nn + gc] = f2bf(1.0f / (1.0f + expf(-vv)));
        }
      }
    }
  }
}

// ---------------- rope in place on q (role 0, + scale) and k (role 1) -----
__global__ void rope_k(short* __restrict__ qkv, const float* __restrict__ tab){
  long idx = (long)blockIdx.x * 256 + threadIdx.x;
  int i8 = (int)(idx & 7);
  long rest = idx >> 3;
  int n = (int)(rest & 8191); rest >>= 13;
  int h = (int)(rest & 15);
  int role = (int)(rest >> 4);
  int i0 = i8 * 8;
  long base = (((long)role * NH + h) * NTOK + n) * HD;
  v8s x1 = *(const v8s*)(qkv + base + i0);
  v8s x2 = *(const v8s*)(qkv + base + 64 + i0);
  v4f c0 = *(const v4f*)(tab + n * 128 + i0);
  v4f c1 = *(const v4f*)(tab + n * 128 + i0 + 4);
  v4f s0 = *(const v4f*)(tab + n * 128 + 64 + i0);
  v4f s1 = *(const v4f*)(tab + n * 128 + 64 + i0 + 4);
  float sc = (role == 0) ? 0.08838834764831845f : 1.0f;
  v8s o1, o2;
#pragma unroll
  for(int j = 0; j < 4; j++){
    float a = bf2f(x1[j]), b = bf2f(x2[j]);
    o1[j] = f2bf((a * c0[j] - b * s0[j]) * sc);
    o2[j] = f2bf((b * c0[j] + a * s0[j]) * sc);
  }
#pragma unroll
  for(int j = 0; j < 4; j++){
    float a = bf2f(x1[4 + j]), b = bf2f(x2[4 + j]);
    o1[4 + j] = f2bf((a * c1[j] - b * s1[j]) * sc);
    o2[4 + j] = f2bf((b * c1[j] + a * s1[j]) * sc);
  }
  *(v8s*)(qkv + base + i0) = o1;
  *(v8s*)(qkv + base + 64 + i0) = o2;
}

// ---------------- per (h,c): S^T[e][d] = sum_n v[n][e] * k[n][d] * kdec[n]
__global__ __launch_bounds__(256)
void skernel(const short* __restrict__ qkv, float* __restrict__ Sb){
  int c = blockIdx.x, h = blockIdx.y;
  float s = slope_of(h);
  __shared__ __align__(16) short kT[128][40];
  __shared__ __align__(16) short vT[128][40];
  const int t = threadIdx.x, lane = t & 63, w = t >> 6;
  const int wm = w >> 1, wn = w & 1;
  const short* kb = qkv + (((long)NH + h) * NTOK + c * CHUNK) * HD;
  const short* vb = qkv + (((long)2 * NH + h) * NTOK + c * CHUNK) * HD;
  v4f acc[4][4];
#pragma unroll
  for(int i = 0; i < 4; i++)
#pragma unroll
    for(int j = 0; j < 4; j++) acc[i][j] = (v4f){0.f, 0.f, 0.f, 0.f};

  for(int n0 = 0; n0 < CHUNK; n0 += 32){
    __syncthreads();
#pragma unroll
    for(int rep = 0; rep < 2; rep++){
      int L = rep * 256 + t;
      int nn = L >> 4, d0 = (L & 15) << 3;
      v8s kx = *(const v8s*)(kb + (long)(n0 + nn) * HD + d0);
      v8s vx = *(const v8s*)(vb + (long)(n0 + nn) * HD + d0);
      float kd = expf(-s * (float)(255 - (n0 + nn)));
#pragma unroll
      for(int j = 0; j < 8; j++){
        kT[d0 + j][nn] = f2bf(bf2f(kx[j]) * kd);
        vT[d0 + j][nn] = vx[j];
      }
    }
    __syncthreads();
    const int lrow = lane & 15, kofs = (lane >> 4) << 3;
    v8s af[4], bfr[4];
#pragma unroll
    for(int ei = 0; ei < 4; ei++) af[ei] = *(const v8s*)&vT[wm * 64 + ei * 16 + lrow][kofs];
#pragma unroll
    for(int di = 0; di < 4; di++) bfr[di] = *(const v8s*)&kT[wn * 64 + di * 16 + lrow][kofs];
#pragma unroll
    for(int ei = 0; ei < 4; ei++)
#pragma unroll
      for(int di = 0; di < 4; di++)
        acc[ei][di] = __builtin_amdgcn_mfma_f32_16x16x32_bf16(af[ei], bfr[di], acc[ei][di], 0, 0, 0);
  }
  float* ob = Sb + ((long)h * NCH + c) * (HD * HD);
  const int crow = (lane >> 4) << 2, ccol = lane & 15;
#pragma unroll
  for(int ei = 0; ei < 4; ei++)
#pragma unroll
    for(int di = 0; di < 4; di++)
#pragma unroll
      for(int r = 0; r < 4; r++)
        ob[(long)(wm * 64 + ei * 16 + crow + r) * HD + wn * 64 + di * 16 + ccol] = acc[ei][di][r];
}

// ---------------- decay-scan over chunks ----------------
__global__ void scan_k(const float* __restrict__ Sb, short* __restrict__ kvb){
  int idx = blockIdx.x * 256 + threadIdx.x;
  int h = idx >> 14, ed = idx & 16383;
  float bd = expf(-slope_of(h) * 256.0f);
  float a = 0.f;
  for(int c = 0; c < NCH; c++){
    long o = ((long)h * NCH + c) * 16384 + ed;
    kvb[o] = f2bf(a);
    a = bd * a + Sb[o];
  }
}

// ---------------- attention output: o_inter + o_intra -> bf16 attnb ------
__global__ __launch_bounds__(256)
void attn_k(const short* __restrict__ qkv, const short* __restrict__ kvb,
            short* __restrict__ attnb){
  const int c = blockIdx.x, mt = blockIdx.y, h = blockIdx.z;
  const int t = threadIdx.x, lane = t & 63, w = t >> 6;
  const float s = slope_of(h);
  __shared__ __align__(16) short Kl[64 * 128];
  __shared__ __align__(16) short VT[128][72];
  const int lrow = lane & 15, kg = lane >> 4;
  const int mbase = mt * 64 + w * 16;

  const short* qb = qkv + (((long)h) * NTOK + c * CHUNK + mbase) * HD;
  v8s qf[4];
#pragma unroll
  for(int kc = 0; kc < 4; kc++)
    qf[kc] = *(const v8s*)(qb + (long)lrow * HD + kc * 32 + kg * 8);

  v4f acc[8];
#pragma unroll
  for(int ei = 0; ei < 8; ei++) acc[ei] = (v4f){0.f, 0.f, 0.f, 0.f};

  const short* kvt = kvb + ((long)h * NCH + c) * 16384;
#pragma unroll
  for(int ei = 0; ei < 8; ei++)
#pragma unroll
    for(int kc = 0; kc < 4; kc++){
      v8s bfr = *(const v8s*)(kvt + (long)(ei * 16 + lrow) * HD + kc * 32 + kg * 8);
      acc[ei] = __builtin_amdgcn_mfma_f32_16x16x32_bf16(qf[kc], bfr, acc[ei], 0, 0, 0);
    }
  float qd[4];
#pragma unroll
  for(int r = 0; r < 4; r++) qd[r] = expf(-s * (float)(mbase + kg * 4 + r + 1));
#pragma unroll
  for(int ei = 0; ei < 8; ei++)
#pragma unroll
    for(int r = 0; r < 4; r++) acc[ei][r] *= qd[r];

  const short* kbase = qkv + (((long)NH + h) * NTOK + c * CHUNK) * HD;
  const short* vbase = qkv + (((long)2 * NH + h) * NTOK + c * CHUNK) * HD;
  for(int nc = 0; nc <= mt; nc++){
    __syncthreads();
#pragma unroll
    for(int rep = 0; rep < 4; rep++){
      int L = rep * 256 + t;
      int nn = L >> 4, d0 = (L & 15) << 3;
      v8s kx = *(const v8s*)(kbase + ((long)nc * 64 + nn) * HD + d0);
      int ba = (nn << 8) + (d0 << 1); ba ^= (nn & 7) << 4;
      *(v8s*)((char*)Kl + ba) = kx;
      v8s vx = *(const v8s*)(vbase + ((long)nc * 64 + nn) * HD + d0);
#pragma unroll
      for(int j = 0; j < 8; j++) VT[d0 + j][nn] = vx[j];
    }
    __syncthreads();
    const int m_gl = mbase + lrow;
#pragma unroll
    for(int nf = 0; nf < 4; nf++){
      v4f pT = (v4f){0.f, 0.f, 0.f, 0.f};
#pragma unroll
      for(int kc = 0; kc < 4; kc++){
        int rr = nf * 16 + lrow;
        int ba = (rr << 8) + ((kc * 32 + kg * 8) << 1); ba ^= (rr & 7) << 4;
        v8s kf = *(const v8s*)((char*)Kl + ba);
        pT = __builtin_amdgcn_mfma_f32_16x16x32_bf16(kf, qf[kc], pT, 0, 0, 0);
      }
      v4s pb;
#pragma unroll
      for(int r = 0; r < 4; r++){
        int n_gl = nc * 64 + nf * 16 + kg * 4 + r;
        float f = (n_gl <= m_gl) ? expf(-s * (float)(m_gl - n_gl)) : 0.f;
        pb[r] = f2bf(pT[r] * f);
      }
#pragma unroll
      for(int ei = 0; ei < 8; ei++){
        v4s vf = *(const v4s*)&VT[ei * 16 + lrow][nf * 16 + kg * 4];
        acc[ei] = __builtin_amdgcn_mfma_f32_16x16x16bf16_1k(pb, vf, acc[ei], 0, 0, 0);
      }
    }
  }

  short* ob = attnb + (long)(c * CHUNK + mbase) * HIDD + h * HD;
#pragma unroll
  for(int ei = 0; ei < 8; ei++)
#pragma unroll
    for(int r = 0; r < 4; r++)
      ob[(long)(kg * 4 + r) * HIDD + ei * 16 + lrow] = f2bf(acc[ei][r]);
}

// ---------------- RMS norm * g_norm_weight * sigmoid(gate) -> bf16 y ------
__global__ __launch_bounds__(256)
void rmsgate_k(const short* __restrict__ attnb, const short* __restrict__ gsig,
               const float* __restrict__ gnw, short* __restrict__ yb){
  int n = blockIdx.x, t = threadIdx.x;
  v8s x = *(const v8s*)(attnb + (long)n * HIDD + t * 8);
  float xf[8]; float ssq = 0.f;
#pragma unroll
  for(int j = 0; j < 8; j++){ xf[j] = bf2f(x[j]); ssq += xf[j] * xf[j]; }
  for(int o = 32; o > 0; o >>= 1) ssq += __shfl_down(ssq, o, 64);
  __shared__ float rl[4];
  int lane = t & 63, w = t >> 6;
  if(lane == 0) rl[w] = ssq;
  __syncthreads();
  float tot = rl[0] + rl[1] + rl[2] + rl[3];
  float rms = rsqrtf(tot * (1.0f / 2048.0f) + 1e-5f);
  v8s g = *(const v8s*)(gsig + (long)n * HIDD + t * 8);
  v4f w0 = *(const v4f*)(gnw + t * 8);
  v4f w1 = *(const v4f*)(gnw + t * 8 + 4);
  v8s y;
#pragma unroll
  for(int j = 0; j < 4; j++) y[j] = f2bf(xf[j] * rms * w0[j] * bf2f(g[j]));
#pragma unroll
  for(int j = 0; j < 4; j++) y[4 + j] = f2bf(xf[4 + j] * rms * w1[j] * bf2f(g[4 + j]));
  *(v8s*)(yb + (long)n * HIDD + t * 8) = y;
}

extern "C" void kernel_launch(void* const* d_in, const int* in_sizes, int n_in,
                              void* d_out, int out_size, void* d_ws, size_t ws_size,
                              hipStream_t stream)
{
  (void)in_sizes; (void)n_in; (void)out_size; (void)ws_size;
  const float* hidden = (const float*)d_in[0];
  const int* positions = (const int*)d_in[1];
  const float* Wqkv = (const float*)d_in[2];
  const float* Wg = (const float*)d_in[3];
  const float* Wd = (const float*)d_in[4];
  const float* gnw = (const float*)d_in[5];
  float* out = (float*)d_out;

  // ---- workspace plan (peak 152 MiB) with lifetime overlays ----
  char* ws = (char*)d_ws;
  const size_t HBF_B = (size_t)NTOK * HIDD * 2;
  const size_t WTR_B = (size_t)NQKV * HIDD * 2;
  const size_t KVB_B = (size_t)NH * NCH * HD * HD * 2;
  short* hbf   = (short*)(ws);
  short* yb    = hbf;
  char*  wtr   = ws + HBF_B;
  short* wqkvT = (short*)(wtr);
  short* kvb   = (short*)(wtr);
  float* tab   = (float*)(wtr + KVB_B);
  short* wgT   = (short*)(wtr + KVB_B);
  short* wdT   = (short*)(wtr);
  short* qkvbf = (short*)(ws + HBF_B + WTR_B);
  float* Sb    = (float*)(d_out);
  short* attnb = (short*)(d_out);
  short* gsig  = (short*)((char*)d_out + (size_t)NTOK * HIDD * 2);

  // 1-3: hidden->bf16, WqkvT, qkv gemm
  cvt_k<<<(NTOK * HIDD / 4) / 256, 256, 0, stream>>>(hidden, hbf, NTOK * HIDD / 4);
  tconv_k<<<dim3(NQKV / 32, HIDD / 32), 256, 0, stream>>>(Wqkv, wqkvT, HIDD, NQKV);
  gemm256_k<1><<<dim3(NQKV / 256, NTOK / 256), 512, 0, stream>>>(hbf, wqkvT, nullptr, qkvbf, NQKV);

  // 4-5: rope
  rope_table_k<<<NTOK, 64, 0, stream>>>(positions, tab);
  rope_k<<<(2 * NH * NTOK * 8) / 256, 256, 0, stream>>>(qkvbf, tab);

  // 6-8: lightning attention
  skernel<<<dim3(NCH, NH), 256, 0, stream>>>(qkvbf, Sb);
  scan_k<<<(NH * HD * HD) / 256, 256, 0, stream>>>(Sb, kvb);
  attn_k<<<dim3(NCH, 4, NH), 256, 0, stream>>>(qkvbf, kvb, attnb);

  // 9-10: gate gemm (sigmoid, bf16)
  tconv_k<<<dim3(HIDD / 32, HIDD / 32), 256, 0, stream>>>(Wg, wgT, HIDD, HIDD);
  gemm256_k<2><<<dim3(HIDD / 256, NTOK / 256), 512, 0, stream>>>(hbf, wgT, nullptr, gsig, HIDD);

  // 11: rms-norm * weight * sigmoid(gate) -> yb
  rmsgate_k<<<NTOK, 256, 0, stream>>>(attnb, gsig, gnw, yb);

  // 12-13: output gemm
  tconv_k<<<dim3(HIDD / 32, HIDD / 32), 256, 0, stream>>>(Wd, wdT, HIDD, HIDD);
  gemm256_k<0><<<dim3(HIDD / 256, NTOK / 256), 512, 0, stream>>>(yb, wdT, out, nullptr, HIDD);
}